// Round 1
// baseline (2645.091 us; speedup 1.0000x reference)
//
#include <hip/hip_runtime.h>
#include <math.h>

// Problem constants
#define NN 325            // nodes
#define BB 8
#define PP 64
#define HH 64             // hidden = C
#define NHEAD 4
#define HD 16             // head dim
#define NROWS (BB*NN*PP)  // 166400 rows of width 64 (both layouts have same count)
#define RELEM ((size_t)NROWS * 64)  // 10,649,600 floats per big buffer

// ---------------------------------------------------------------------------
// Kernel 0: transpose weights into ws so all projection inner loops read
// coalesced (cc-major) weights.
//  wt[0      .. 12288)  : ipwT[t*4096 + cc*64 + j] = in_proj_w[(t*64+j)*64+cc]
//  wt[12288  .. 16384)  : outwT[cc*64 + j]         = out_w[j*64+cc]
//  wt[16384  .. 20480)  : woutT[h*64 + c]          = W_out[c*64+h]   (note: y[c]=sum_h t1[h]*W_out[c][h])
// ---------------------------------------------------------------------------
__global__ __launch_bounds__(256) void kprep(const float* __restrict__ ipw,
                                             const float* __restrict__ outw,
                                             const float* __restrict__ wout,
                                             float* __restrict__ wt) {
    int idx = blockIdx.x * 256 + threadIdx.x;   // grid covers exactly 20480
    if (idx < 12288) {
        int t = idx >> 12, rem = idx & 4095;
        int cc = rem >> 6, j = rem & 63;
        wt[idx] = ipw[(t * 64 + j) * 64 + cc];
    } else if (idx < 16384) {
        int i2 = idx - 12288;
        int cc = i2 >> 6, j = i2 & 63;
        wt[idx] = outw[j * 64 + cc];
    } else {
        int i2 = idx - 16384;
        int h = i2 >> 6, c = i2 & 63;
        wt[idx] = wout[c * 64 + h];
    }
}

// ---------------------------------------------------------------------------
// Kernel 1: input projection  h = x @ W_in + b_in   (W_in already cc-major)
// 4 rows per block, one wave per row.
// ---------------------------------------------------------------------------
__global__ __launch_bounds__(256) void kproj_in(const float* __restrict__ X,
                                                const float* __restrict__ W,
                                                const float* __restrict__ bias,
                                                float* __restrict__ Y) {
    __shared__ float xs[256];
    int r = threadIdx.x >> 6, j = threadIdx.x & 63;
    size_t base = (size_t)blockIdx.x * 256;
    xs[threadIdx.x] = X[base + threadIdx.x];
    __syncthreads();
    const float* xr = &xs[r * 64];
    float acc = bias[j];
#pragma unroll
    for (int cc = 0; cc < 64; ++cc) acc = fmaf(xr[cc], W[cc * 64 + j], acc);
    Y[base + r * 64 + j] = acc;
}

// ---------------------------------------------------------------------------
// Kernel 2: QKV projection from h (flat reinterpret handles the .view)
// ---------------------------------------------------------------------------
__global__ __launch_bounds__(256) void kqkv(const float* __restrict__ Hb,
                                            const float* __restrict__ ipwT,
                                            const float* __restrict__ ipb,
                                            float* __restrict__ Q,
                                            float* __restrict__ K,
                                            float* __restrict__ V) {
    __shared__ float xs[256];
    int r = threadIdx.x >> 6, j = threadIdx.x & 63;
    size_t base = (size_t)blockIdx.x * 256;
    xs[threadIdx.x] = Hb[base + threadIdx.x];
    __syncthreads();
    const float* xr = &xs[r * 64];
#pragma unroll
    for (int t = 0; t < 3; ++t) {
        float acc = ipb[t * 64 + j];
        const float* w = ipwT + t * 4096;
#pragma unroll
        for (int cc = 0; cc < 64; ++cc) acc = fmaf(xr[cc], w[cc * 64 + j], acc);
        if (t == 0)      Q[base + r * 64 + j] = acc;
        else if (t == 1) K[base + r * 64 + j] = acc;
        else             V[base + r * 64 + j] = acc;
    }
}

// ---------------------------------------------------------------------------
// Kernel 3: masked MHA per (bp, head). Block = 256 (4 waves).
// K,V head-slices in LDS with stride 17 (2-way bank aliasing only = free).
// One wave per query row; lanes cover keys; shuffle softmax; per-wave LDS
// p-buffer for the PV product.
// ---------------------------------------------------------------------------
__global__ __launch_bounds__(256) void kattn(const float* __restrict__ Q,
                                             const float* __restrict__ K,
                                             const float* __restrict__ V,
                                             const int* __restrict__ adj,
                                             float* __restrict__ O) {
    __shared__ float ks[NN * 17];
    __shared__ float vs[NN * 17];
    __shared__ float pbuf[4][328];
    int bp = blockIdx.x >> 2, head = blockIdx.x & 3;
    size_t gbase = (size_t)bp * (NN * 64) + head * HD;

    for (int idx = threadIdx.x; idx < NN * HD; idx += 256) {
        int n = idx >> 4, d = idx & 15;
        size_t ga = gbase + (size_t)n * 64 + d;
        ks[n * 17 + d] = K[ga];
        vs[n * 17 + d] = V[ga];
    }
    __syncthreads();

    int wave = threadIdx.x >> 6, lane = threadIdx.x & 63;
    for (int qi = 0; qi < 82; ++qi) {
        int qn = qi * 4 + wave;
        bool active = qn < NN;
        if (active) {
            float qreg[16];
            size_t qa = gbase + (size_t)qn * 64;
#pragma unroll
            for (int d = 0; d < 16; ++d) qreg[d] = Q[qa + d];

            const int* arow = adj + qn * NN;
            float s[6];
            float m = -INFINITY;
#pragma unroll
            for (int c = 0; c < 6; ++c) {
                int kn = c * 64 + lane;
                float sc = -INFINITY;
                if (kn < NN && (kn == qn || arow[kn] != 0)) {
                    float dotv = 0.f;
#pragma unroll
                    for (int d = 0; d < 16; ++d)
                        dotv = fmaf(qreg[d], ks[kn * 17 + d], dotv);
                    sc = dotv * 0.25f;   // 1/sqrt(16)
                }
                s[c] = sc;
                m = fmaxf(m, sc);
            }
#pragma unroll
            for (int off = 32; off; off >>= 1) m = fmaxf(m, __shfl_xor(m, off));
            float sum = 0.f;
#pragma unroll
            for (int c = 0; c < 6; ++c) { s[c] = __expf(s[c] - m); sum += s[c]; }
#pragma unroll
            for (int off = 32; off; off >>= 1) sum += __shfl_xor(sum, off);
            float inv = 1.0f / sum;
#pragma unroll
            for (int c = 0; c < 6; ++c) {
                int kn = c * 64 + lane;
                if (kn < NN) pbuf[wave][kn] = s[c] * inv;
            }
        }
        __syncthreads();   // order pbuf write -> read (uniform across block)
        if (active) {
            int d = lane & 15, g = lane >> 4;
            float acc = 0.f;
            for (int kn = g; kn < NN; kn += 4)
                acc = fmaf(pbuf[wave][kn], vs[kn * 17 + d], acc);
            acc += __shfl_xor(acc, 16);
            acc += __shfl_xor(acc, 32);
            if (lane < 16) O[gbase + (size_t)qn * 64 + d] = acc;
        }
        __syncthreads();
    }
}

// ---------------------------------------------------------------------------
// Kernel 4: out_proj -> W_out -> exact GELU -> transpose to (B,N,P,C)
// row r (in (bp,n) order): bp=r/325, n=r%325, b=bp/64, p=bp%64
// out[((b*325+n)*64+p)*64 + c]
// ---------------------------------------------------------------------------
__global__ __launch_bounds__(256) void kfinal(const float* __restrict__ Ob,
                                              const float* __restrict__ outwT,
                                              const float* __restrict__ outb,
                                              const float* __restrict__ woutT,
                                              const float* __restrict__ boutv,
                                              float* __restrict__ Yout) {
    __shared__ float xs[256];
    __shared__ float t1s[256];
    int r = threadIdx.x >> 6, j = threadIdx.x & 63;
    size_t base = (size_t)blockIdx.x * 256;
    xs[threadIdx.x] = Ob[base + threadIdx.x];
    __syncthreads();
    const float* xr = &xs[r * 64];
    float acc = outb[j];
#pragma unroll
    for (int cc = 0; cc < 64; ++cc) acc = fmaf(xr[cc], outwT[cc * 64 + j], acc);
    t1s[r * 64 + j] = acc;
    __syncthreads();
    const float* tr = &t1s[r * 64];
    float acc2 = boutv[j];
#pragma unroll
    for (int cc = 0; cc < 64; ++cc) acc2 = fmaf(tr[cc], woutT[cc * 64 + j], acc2);
    float g = 0.5f * acc2 * (1.0f + erff(acc2 * 0.70710678118654752f));

    int row = blockIdx.x * 4 + r;
    int bp = row / NN, n = row - bp * NN;
    int b = bp >> 6, p = bp & 63;
    size_t oidx = ((((size_t)b * NN + n) * 64 + p) * 64) + j;
    Yout[oidx] = g;
}

// ---------------------------------------------------------------------------
extern "C" void kernel_launch(void* const* d_in, const int* in_sizes, int n_in,
                              void* d_out, int out_size, void* d_ws, size_t ws_size,
                              hipStream_t stream) {
    const float* x    = (const float*)d_in[0];
    const int*   adj  = (const int*)  d_in[1];
    const float* W_in = (const float*)d_in[2];
    const float* b_in = (const float*)d_in[3];
    const float* ipw  = (const float*)d_in[4];
    const float* ipb  = (const float*)d_in[5];
    const float* outw = (const float*)d_in[6];
    const float* outb = (const float*)d_in[7];
    const float* wout = (const float*)d_in[8];
    const float* bout = (const float*)d_in[9];
    float* out = (float*)d_out;

    float* ws   = (float*)d_ws;
    float* bufH = ws;                 // h, later reused for attention output o
    float* bufQ = ws + RELEM;
    float* bufK = ws + 2 * RELEM;
    float* bufV = ws + 3 * RELEM;
    float* wt   = ws + 4 * RELEM;     // 20480 floats of transposed weights

    const int rowBlocks = NROWS / 4;  // 41600

    hipLaunchKernelGGL(kprep,    dim3(80),        dim3(256), 0, stream, ipw, outw, wout, wt);
    hipLaunchKernelGGL(kproj_in, dim3(rowBlocks), dim3(256), 0, stream, x, W_in, b_in, bufH);
    hipLaunchKernelGGL(kqkv,     dim3(rowBlocks), dim3(256), 0, stream, bufH, wt, ipb, bufQ, bufK, bufV);
    hipLaunchKernelGGL(kattn,    dim3(512 * NHEAD), dim3(256), 0, stream, bufQ, bufK, bufV, adj, bufH);
    hipLaunchKernelGGL(kfinal,   dim3(rowBlocks), dim3(256), 0, stream,
                       bufH, wt + 12288, outb, wt + 16384, bout, out);
}

// Round 2
// 2079.943 us; speedup vs baseline: 1.2717x; 1.2717x over previous
//
#include <hip/hip_runtime.h>
#include <math.h>

// Problem constants
#define NN 325            // nodes
#define NROWS (8*325*64)  // 166400 rows of width 64
#define RELEM ((size_t)NROWS * 64)

// ---------------------------------------------------------------------------
// Kernel 0: transpose weights so projection inner loops read cc-major.
//  wt[0     .. 12288) : ipwT[t*4096 + cc*64 + j] = in_proj_w[(t*64+j)*64+cc]
//  wt[12288 .. 16384) : outwT[cc*64 + j]         = out_w[j*64+cc]
//  wt[16384 .. 20480) : woutT[h*64 + c]          = W_out[c*64+h]
// ---------------------------------------------------------------------------
__global__ __launch_bounds__(256) void kprep(const float* __restrict__ ipw,
                                             const float* __restrict__ outw,
                                             const float* __restrict__ wout,
                                             float* __restrict__ wt) {
    int idx = blockIdx.x * 256 + threadIdx.x;
    if (idx < 12288) {
        int t = idx >> 12, rem = idx & 4095;
        int cc = rem >> 6, j = rem & 63;
        wt[idx] = ipw[(t * 64 + j) * 64 + cc];
    } else if (idx < 16384) {
        int i2 = idx - 12288;
        int cc = i2 >> 6, j = i2 & 63;
        wt[idx] = outw[j * 64 + cc];
    } else {
        int i2 = idx - 16384;
        int h = i2 >> 6, c = i2 & 63;
        wt[idx] = wout[c * 64 + h];
    }
}

// ---------------------------------------------------------------------------
// Kernel 1: fused x -> h -> Q,K,V.  16 rows per block; weight column held in
// 64 VGPRs (amortized over 16 rows); x/h rows broadcast from LDS.
// ---------------------------------------------------------------------------
__global__ __launch_bounds__(256) void kqkv(const float* __restrict__ X,
                                            const float* __restrict__ Win,
                                            const float* __restrict__ bin,
                                            const float* __restrict__ ipwT,
                                            const float* __restrict__ ipb,
                                            float* __restrict__ Q,
                                            float* __restrict__ K,
                                            float* __restrict__ V) {
    __shared__ float xs[16 * 64];
    __shared__ float hs[16 * 64];
    int tid = threadIdx.x;
    size_t rbase = (size_t)blockIdx.x * 16;

    ((float4*)xs)[tid] = ((const float4*)(X + rbase * 64))[tid];
    __syncthreads();

    int r4 = tid >> 6, j = tid & 63;
    float wr[64];
#pragma unroll
    for (int cc = 0; cc < 64; ++cc) wr[cc] = Win[cc * 64 + j];
#pragma unroll
    for (int rr0 = 0; rr0 < 4; ++rr0) {
        int rr = rr0 * 4 + r4;
        const float* xrow = xs + rr * 64;
        float acc = bin[j];
#pragma unroll
        for (int cc = 0; cc < 64; ++cc) acc = fmaf(xrow[cc], wr[cc], acc);
        hs[rr * 64 + j] = acc;
    }
    __syncthreads();

#pragma unroll
    for (int t = 0; t < 3; ++t) {
#pragma unroll
        for (int cc = 0; cc < 64; ++cc) wr[cc] = ipwT[t * 4096 + cc * 64 + j];
        float* Out = (t == 0) ? Q : (t == 1) ? K : V;
        float bb = ipb[t * 64 + j];
#pragma unroll
        for (int rr0 = 0; rr0 < 4; ++rr0) {
            int rr = rr0 * 4 + r4;
            const float* hrow = hs + rr * 64;
            float acc = bb;
#pragma unroll
            for (int cc = 0; cc < 64; ++cc) acc = fmaf(hrow[cc], wr[cc], acc);
            Out[(rbase + rr) * 64 + j] = acc;
        }
    }
}

// ---------------------------------------------------------------------------
// Kernel 2: masked MHA, one block per (bp, head), 4 waves, NO per-row
// barriers (pbuf is per-wave; same-wave LDS RAW is ordered by lgkmcnt).
// Each wave batches M=4 query rows per pass: K-tile LDS reads amortized 4x,
// Q read as wave-uniform global broadcasts, PV via per-wave LDS transpose
// with conflict-free patterns. LDS total = 54,600 B -> 3 blocks/CU.
// ---------------------------------------------------------------------------
__global__ __launch_bounds__(256, 2) void kattn(const float* __restrict__ Q,
                                                const float* __restrict__ K,
                                                const float* __restrict__ V,
                                                const int* __restrict__ adj,
                                                float* __restrict__ O) {
    __shared__ float ks[NN * 17];        // 22100 B, stride 17 -> 2-way only
    __shared__ float vs[NN * 17];        // 22100 B
    __shared__ float pbuf[4 * 2 * NN];   // 10400 B, per-wave double row
    int bp = blockIdx.x >> 2, head = blockIdx.x & 3;
    size_t gbase = (size_t)bp * (NN * 64) + head * 16;
    int tid = threadIdx.x;

    // stage K,V head-slices (float4 global loads, scalar LDS writes)
    for (int idx = tid; idx < NN * 4; idx += 256) {
        int n = idx >> 2, d4 = idx & 3;
        float4 kv = *(const float4*)(K + gbase + (size_t)n * 64 + d4 * 4);
        float4 vv = *(const float4*)(V + gbase + (size_t)n * 64 + d4 * 4);
        int a = n * 17 + d4 * 4;
        ks[a + 0] = kv.x; ks[a + 1] = kv.y; ks[a + 2] = kv.z; ks[a + 3] = kv.w;
        vs[a + 0] = vv.x; vs[a + 1] = vv.y; vs[a + 2] = vv.z; vs[a + 3] = vv.w;
    }
    __syncthreads();   // the only barrier

    int wave = tid >> 6, lane = tid & 63;
    int wstart = wave * 82;
    int wend = (wstart + 82 < NN) ? wstart + 82 : NN;
    float* pb = pbuf + wave * (2 * NN);
    int d4 = lane & 3, g = lane >> 2;

    for (int qn0 = wstart; qn0 < wend; qn0 += 4) {
        int qn[4];
        float q[4][16];
#pragma unroll
        for (int m = 0; m < 4; ++m) {
            int qq = qn0 + m;
            qn[m] = (qq < wend) ? qq : (wend - 1);
            const float* qp = Q + gbase + (size_t)qn[m] * 64;
            float4 a0 = *(const float4*)(qp + 0);
            float4 a1 = *(const float4*)(qp + 4);
            float4 a2 = *(const float4*)(qp + 8);
            float4 a3 = *(const float4*)(qp + 12);
            q[m][0] = a0.x; q[m][1] = a0.y; q[m][2]  = a0.z; q[m][3]  = a0.w;
            q[m][4] = a1.x; q[m][5] = a1.y; q[m][6]  = a1.z; q[m][7]  = a1.w;
            q[m][8] = a2.x; q[m][9] = a2.y; q[m][10] = a2.z; q[m][11] = a2.w;
            q[m][12] = a3.x; q[m][13] = a3.y; q[m][14] = a3.z; q[m][15] = a3.w;
        }

        float e[4][6];
#pragma unroll
        for (int c = 0; c < 6; ++c) {
            int kn = c * 64 + lane;
            bool inr = kn < NN;
            int am[4];
#pragma unroll
            for (int m = 0; m < 4; ++m)
                am[m] = inr ? adj[qn[m] * NN + kn] : 0;
            float dot[4] = {0.f, 0.f, 0.f, 0.f};
            if (inr) {
#pragma unroll
                for (int d = 0; d < 16; ++d) {
                    float kv = ks[kn * 17 + d];
#pragma unroll
                    for (int m = 0; m < 4; ++m)
                        dot[m] = fmaf(q[m][d], kv, dot[m]);
                }
            }
#pragma unroll
            for (int m = 0; m < 4; ++m)
                e[m][c] = (inr && (am[m] != 0 || kn == qn[m]))
                              ? dot[m] * 0.25f : -INFINITY;
        }

        float inv[4];
#pragma unroll
        for (int m = 0; m < 4; ++m) {
            float mx = e[m][0];
#pragma unroll
            for (int c = 1; c < 6; ++c) mx = fmaxf(mx, e[m][c]);
#pragma unroll
            for (int off = 32; off; off >>= 1) mx = fmaxf(mx, __shfl_xor(mx, off));
            float sum = 0.f;
#pragma unroll
            for (int c = 0; c < 6; ++c) { e[m][c] = __expf(e[m][c] - mx); sum += e[m][c]; }
#pragma unroll
            for (int off = 32; off; off >>= 1) sum += __shfl_xor(sum, off);
            inv[m] = 1.0f / sum;
        }

        // PV: two sub-passes of 2 rows through the per-wave transpose buffer
#pragma unroll
        for (int sub = 0; sub < 2; ++sub) {
            int m0 = sub * 2, m1 = m0 + 1;
#pragma unroll
            for (int c = 0; c < 6; ++c) {
                int kn = c * 64 + lane;
                if (kn < NN) { pb[kn] = e[m0][c]; pb[NN + kn] = e[m1][c]; }
            }
            float4 o0 = {0.f, 0.f, 0.f, 0.f}, o1 = {0.f, 0.f, 0.f, 0.f};
#pragma unroll
            for (int i = 0; i < 21; ++i) {
                int kn = i * 16 + g;
                if (kn < NN) {
                    float p0 = pb[kn], p1 = pb[NN + kn];
                    const float* vrow = vs + kn * 17 + d4 * 4;
                    float v0 = vrow[0], v1 = vrow[1], v2 = vrow[2], v3 = vrow[3];
                    o0.x = fmaf(p0, v0, o0.x); o0.y = fmaf(p0, v1, o0.y);
                    o0.z = fmaf(p0, v2, o0.z); o0.w = fmaf(p0, v3, o0.w);
                    o1.x = fmaf(p1, v0, o1.x); o1.y = fmaf(p1, v1, o1.y);
                    o1.z = fmaf(p1, v2, o1.z); o1.w = fmaf(p1, v3, o1.w);
                }
            }
#pragma unroll
            for (int off = 4; off <= 32; off <<= 1) {
                o0.x += __shfl_xor(o0.x, off); o0.y += __shfl_xor(o0.y, off);
                o0.z += __shfl_xor(o0.z, off); o0.w += __shfl_xor(o0.w, off);
                o1.x += __shfl_xor(o1.x, off); o1.y += __shfl_xor(o1.y, off);
                o1.z += __shfl_xor(o1.z, off); o1.w += __shfl_xor(o1.w, off);
            }
            if (g == 0) {
                if (qn0 + m0 < wend) {
                    float4 r; r.x = o0.x * inv[m0]; r.y = o0.y * inv[m0];
                    r.z = o0.z * inv[m0]; r.w = o0.w * inv[m0];
                    *(float4*)(O + gbase + (size_t)qn[m0] * 64 + d4 * 4) = r;
                }
                if (qn0 + m1 < wend) {
                    float4 r; r.x = o1.x * inv[m1]; r.y = o1.y * inv[m1];
                    r.z = o1.z * inv[m1]; r.w = o1.w * inv[m1];
                    *(float4*)(O + gbase + (size_t)qn[m1] * 64 + d4 * 4) = r;
                }
            }
        }
    }
}

// ---------------------------------------------------------------------------
// Kernel 3: out_proj -> W_out -> exact GELU -> transpose to (B,N,P,C).
// Same 16-row W-in-VGPR structure as kqkv.
// ---------------------------------------------------------------------------
__global__ __launch_bounds__(256) void kfinal(const float* __restrict__ Ob,
                                              const float* __restrict__ outwT,
                                              const float* __restrict__ outb,
                                              const float* __restrict__ woutT,
                                              const float* __restrict__ boutv,
                                              float* __restrict__ Yout) {
    __shared__ float xs[16 * 64];
    __shared__ float t1s[16 * 64];
    int tid = threadIdx.x;
    size_t rbase = (size_t)blockIdx.x * 16;

    ((float4*)xs)[tid] = ((const float4*)(Ob + rbase * 64))[tid];
    __syncthreads();

    int r4 = tid >> 6, j = tid & 63;
    float wr[64];
#pragma unroll
    for (int cc = 0; cc < 64; ++cc) wr[cc] = outwT[cc * 64 + j];
#pragma unroll
    for (int rr0 = 0; rr0 < 4; ++rr0) {
        int rr = rr0 * 4 + r4;
        const float* xrow = xs + rr * 64;
        float acc = outb[j];
#pragma unroll
        for (int cc = 0; cc < 64; ++cc) acc = fmaf(xrow[cc], wr[cc], acc);
        t1s[rr * 64 + j] = acc;
    }
    __syncthreads();

#pragma unroll
    for (int cc = 0; cc < 64; ++cc) wr[cc] = woutT[cc * 64 + j];
    float bb = boutv[j];
#pragma unroll
    for (int rr0 = 0; rr0 < 4; ++rr0) {
        int rr = rr0 * 4 + r4;
        const float* trow = t1s + rr * 64;
        float acc = bb;
#pragma unroll
        for (int cc = 0; cc < 64; ++cc) acc = fmaf(trow[cc], wr[cc], acc);
        float gl = 0.5f * acc * (1.0f + erff(acc * 0.70710678118654752f));

        unsigned row = (unsigned)(rbase + rr);
        unsigned bp = row / NN, n = row - bp * NN;
        unsigned b = bp >> 6, p = bp & 63;
        size_t oidx = ((((size_t)b * NN + n) * 64 + p) * 64) + j;
        Yout[oidx] = gl;
    }
}

// ---------------------------------------------------------------------------
extern "C" void kernel_launch(void* const* d_in, const int* in_sizes, int n_in,
                              void* d_out, int out_size, void* d_ws, size_t ws_size,
                              hipStream_t stream) {
    const float* x    = (const float*)d_in[0];
    const int*   adj  = (const int*)  d_in[1];
    const float* W_in = (const float*)d_in[2];
    const float* b_in = (const float*)d_in[3];
    const float* ipw  = (const float*)d_in[4];
    const float* ipb  = (const float*)d_in[5];
    const float* outw = (const float*)d_in[6];
    const float* outb = (const float*)d_in[7];
    const float* wout = (const float*)d_in[8];
    const float* bout = (const float*)d_in[9];
    float* out = (float*)d_out;

    float* ws   = (float*)d_ws;
    float* bufQ = ws;
    float* bufK = ws + RELEM;
    float* bufV = ws + 2 * RELEM;
    float* bufO = ws + 3 * RELEM;
    float* wt   = ws + 4 * RELEM;     // 20480 floats of transposed weights

    hipLaunchKernelGGL(kprep,  dim3(80),    dim3(256), 0, stream, ipw, outw, wout, wt);
    hipLaunchKernelGGL(kqkv,   dim3(NROWS / 16), dim3(256), 0, stream,
                       x, W_in, b_in, wt, ipb, bufQ, bufK, bufV);
    hipLaunchKernelGGL(kattn,  dim3(512 * 4), dim3(256), 0, stream,
                       bufQ, bufK, bufV, adj, bufO);
    hipLaunchKernelGGL(kfinal, dim3(NROWS / 16), dim3(256), 0, stream,
                       bufO, wt + 12288, outb, wt + 16384, bout, out);
}

// Round 3
// 1460.408 us; speedup vs baseline: 1.8112x; 1.4242x over previous
//
#include <hip/hip_runtime.h>
#include <math.h>

// Problem constants
#define NN 325            // nodes
#define NROWS (8*325*64)  // 166400 rows of width 64
#define RELEM ((size_t)NROWS * 64)
#define KS 20             // ks/vs row stride in floats (80 B, 16B-aligned, conflict-free)
#define NKPAD 384         // ks rows (score reads kn up to 383; masked lanes read garbage safely)
#define NVPAD 336         // vs/pbuf rows (PV reads kn up to 335; rows >=325 are zero / p=0)

// ---------------------------------------------------------------------------
// Kernel 0: transpose weights so projection inner loops read cc-major.
//  wt[0     .. 12288) : ipwT[t*4096 + cc*64 + j] = in_proj_w[(t*64+j)*64+cc]
//  wt[12288 .. 16384) : outwT[cc*64 + j]         = out_w[j*64+cc]
//  wt[16384 .. 20480) : woutT[h*64 + c]          = W_out[c*64+h]
// ---------------------------------------------------------------------------
__global__ __launch_bounds__(256) void kprep(const float* __restrict__ ipw,
                                             const float* __restrict__ outw,
                                             const float* __restrict__ wout,
                                             float* __restrict__ wt) {
    int idx = blockIdx.x * 256 + threadIdx.x;
    if (idx < 12288) {
        int t = idx >> 12, rem = idx & 4095;
        int cc = rem >> 6, j = rem & 63;
        wt[idx] = ipw[(t * 64 + j) * 64 + cc];
    } else if (idx < 16384) {
        int i2 = idx - 12288;
        int cc = i2 >> 6, j = i2 & 63;
        wt[idx] = outw[j * 64 + cc];
    } else {
        int i2 = idx - 16384;
        int h = i2 >> 6, c = i2 & 63;
        wt[idx] = wout[c * 64 + h];
    }
}

// ---------------------------------------------------------------------------
// Kernel 0b: adjacency -> bitmask. Word (n,c) bit i = valid(kn=c*64+i):
// kn<NN && (edge || self-loop). 1950 u64 = 15.6 KB total, L2-resident.
// ---------------------------------------------------------------------------
__global__ __launch_bounds__(256) void kmask(const int* __restrict__ adj,
                                             unsigned long long* __restrict__ MB) {
    int t = blockIdx.x * 256 + threadIdx.x;
    if (t < NN * 6) {
        int n = t / 6, c = t % 6;
        unsigned long long w = 0ull;
        for (int i = 0; i < 64; ++i) {
            int kn = c * 64 + i;
            if (kn < NN && (kn == n || adj[n * NN + kn] != 0))
                w |= (1ull << i);
        }
        MB[t] = w;
    }
}

// ---------------------------------------------------------------------------
// Kernel 1: fused x -> h -> Q,K,V. 64 rows/block (weight VGPR refills
// amortized 16 rows/thread), x/h rows broadcast from LDS.
// ---------------------------------------------------------------------------
__global__ __launch_bounds__(256) void kqkv(const float* __restrict__ X,
                                            const float* __restrict__ Win,
                                            const float* __restrict__ bin,
                                            const float* __restrict__ ipwT,
                                            const float* __restrict__ ipb,
                                            float* __restrict__ Q,
                                            float* __restrict__ K,
                                            float* __restrict__ V) {
    __shared__ float xs[64 * 64];
    __shared__ float hs[64 * 64];
    int tid = threadIdx.x;
    size_t rbase = (size_t)blockIdx.x * 64;

    const float4* xp = (const float4*)(X + rbase * 64);
    float4* xs4 = (float4*)xs;
#pragma unroll
    for (int i = 0; i < 4; ++i) xs4[tid + 256 * i] = xp[tid + 256 * i];
    __syncthreads();

    int j = tid & 63, r4 = tid >> 6;
    float wr[64];
#pragma unroll
    for (int cc = 0; cc < 64; ++cc) wr[cc] = Win[cc * 64 + j];
    float bb = bin[j];
    for (int rr = r4; rr < 64; rr += 4) {
        const float* xrow = xs + rr * 64;
        float acc = bb;
#pragma unroll
        for (int cc = 0; cc < 64; ++cc) acc = fmaf(xrow[cc], wr[cc], acc);
        hs[rr * 64 + j] = acc;
    }
    __syncthreads();

#pragma unroll
    for (int t = 0; t < 3; ++t) {
#pragma unroll
        for (int cc = 0; cc < 64; ++cc) wr[cc] = ipwT[t * 4096 + cc * 64 + j];
        float* Out = (t == 0) ? Q : (t == 1) ? K : V;
        float tb = ipb[t * 64 + j];
        for (int rr = r4; rr < 64; rr += 4) {
            const float* hrow = hs + rr * 64;
            float acc = tb;
#pragma unroll
            for (int cc = 0; cc < 64; ++cc) acc = fmaf(hrow[cc], wr[cc], acc);
            Out[(rbase + rr) * 64 + j] = acc;
        }
    }
}

// ---------------------------------------------------------------------------
// Kernel 2: masked MHA, one block per (bp, head), 4 waves, one barrier.
// m=4 query rows per wave pass; adjacency via L2-resident bitmask (no adj
// array reads); no max-subtraction (|scores|<0.01, exp cannot overflow);
// softmax denominator folded into the PV butterfly; all LDS ops b128.
// LDS = 79,104 B -> 2 blocks/CU.
// ---------------------------------------------------------------------------
__global__ __launch_bounds__(256, 2) void kattn(const float* __restrict__ Q,
                                                const float* __restrict__ K,
                                                const float* __restrict__ V,
                                                const unsigned long long* __restrict__ MB,
                                                float* __restrict__ O) {
    __shared__ float ks[NKPAD * KS];       // 30720 B
    __shared__ float vs[NVPAD * KS];       // 26880 B
    __shared__ float pbuf[4][NVPAD * 4];   // 21504 B (per-wave, PS=4)
    int bp = blockIdx.x >> 2, head = blockIdx.x & 3;
    size_t gbase = (size_t)bp * (NN * 64) + head * 16;
    int tid = threadIdx.x;

    // stage K,V head-slices; zero rows [325,336) of both (PV touches vs there)
    for (int idx = tid; idx < NVPAD * 4; idx += 256) {
        int n = idx >> 2, d4 = idx & 3;
        float4 kv = {0.f, 0.f, 0.f, 0.f}, vv = {0.f, 0.f, 0.f, 0.f};
        if (n < NN) {
            kv = *(const float4*)(K + gbase + (size_t)n * 64 + d4 * 4);
            vv = *(const float4*)(V + gbase + (size_t)n * 64 + d4 * 4);
        }
        *(float4*)(ks + n * KS + d4 * 4) = kv;
        *(float4*)(vs + n * KS + d4 * 4) = vv;
    }
    __syncthreads();   // the only barrier

    int wave = tid >> 6, lane = tid & 63;
    int wstart = wave * 82;
    int wend = (wstart + 82 < NN) ? wstart + 82 : NN;
    float* pb = pbuf[wave];
    int d4 = lane & 3, g = lane >> 2;

    for (int qn0 = wstart; qn0 < wend; qn0 += 4) {
        int qn[4];
        float q[4][16];
#pragma unroll
        for (int m = 0; m < 4; ++m) {
            int qq = qn0 + m;
            qn[m] = (qq < wend) ? qq : (wend - 1);
            const float* qp = Q + gbase + (size_t)qn[m] * 64;
            float4 a0 = *(const float4*)(qp + 0);
            float4 a1 = *(const float4*)(qp + 4);
            float4 a2 = *(const float4*)(qp + 8);
            float4 a3 = *(const float4*)(qp + 12);
            q[m][0]  = a0.x; q[m][1]  = a0.y; q[m][2]  = a0.z; q[m][3]  = a0.w;
            q[m][4]  = a1.x; q[m][5]  = a1.y; q[m][6]  = a1.z; q[m][7]  = a1.w;
            q[m][8]  = a2.x; q[m][9]  = a2.y; q[m][10] = a2.z; q[m][11] = a2.w;
            q[m][12] = a3.x; q[m][13] = a3.y; q[m][14] = a3.z; q[m][15] = a3.w;
        }

        // ---- score + exp, straight into per-wave pbuf (p=0 where masked) ----
#pragma unroll
        for (int c = 0; c < 6; ++c) {
            int kn = c * 64 + lane;
            const float* kp = ks + kn * KS;
            float4 k0 = *(const float4*)(kp + 0);
            float4 k1 = *(const float4*)(kp + 4);
            float4 k2 = *(const float4*)(kp + 8);
            float4 k3 = *(const float4*)(kp + 12);
            float kr[16] = {k0.x, k0.y, k0.z, k0.w, k1.x, k1.y, k1.z, k1.w,
                            k2.x, k2.y, k2.z, k2.w, k3.x, k3.y, k3.z, k3.w};
            float dot[4] = {0.f, 0.f, 0.f, 0.f};
#pragma unroll
            for (int d = 0; d < 16; ++d) {
                float kv = kr[d];
#pragma unroll
                for (int m = 0; m < 4; ++m) dot[m] = fmaf(q[m][d], kv, dot[m]);
            }
            float p[4];
#pragma unroll
            for (int m = 0; m < 4; ++m) {
                unsigned long long mw = MB[qn[m] * 6 + c];
                bool on = (mw >> lane) & 1ull;
                float ev = __expf(dot[m] * 0.25f);   // 1/sqrt(16)
                p[m] = on ? ev : 0.0f;               // cndmask: NaN from pad rows discarded
            }
            if (kn < NVPAD) {
                float4 pw; pw.x = p[0]; pw.y = p[1]; pw.z = p[2]; pw.w = p[3];
                *(float4*)(pb + kn * 4) = pw;
            }
        }

        // ---- PV sweep + denominator, single pass over all kn ----
        float o[4][4] = {{0.f,0.f,0.f,0.f},{0.f,0.f,0.f,0.f},
                         {0.f,0.f,0.f,0.f},{0.f,0.f,0.f,0.f}};
        float se[4] = {0.f, 0.f, 0.f, 0.f};
        for (int i = 0; i < 21; ++i) {
            int kn = i * 16 + g;                       // max 335 < NVPAD
            float4 pv = *(const float4*)(pb + kn * 4);
            float4 vv = *(const float4*)(vs + kn * KS + d4 * 4);
            o[0][0] = fmaf(pv.x, vv.x, o[0][0]); o[0][1] = fmaf(pv.x, vv.y, o[0][1]);
            o[0][2] = fmaf(pv.x, vv.z, o[0][2]); o[0][3] = fmaf(pv.x, vv.w, o[0][3]);
            o[1][0] = fmaf(pv.y, vv.x, o[1][0]); o[1][1] = fmaf(pv.y, vv.y, o[1][1]);
            o[1][2] = fmaf(pv.y, vv.z, o[1][2]); o[1][3] = fmaf(pv.y, vv.w, o[1][3]);
            o[2][0] = fmaf(pv.z, vv.x, o[2][0]); o[2][1] = fmaf(pv.z, vv.y, o[2][1]);
            o[2][2] = fmaf(pv.z, vv.z, o[2][2]); o[2][3] = fmaf(pv.z, vv.w, o[2][3]);
            o[3][0] = fmaf(pv.w, vv.x, o[3][0]); o[3][1] = fmaf(pv.w, vv.y, o[3][1]);
            o[3][2] = fmaf(pv.w, vv.z, o[3][2]); o[3][3] = fmaf(pv.w, vv.w, o[3][3]);
            se[0] += pv.x; se[1] += pv.y; se[2] += pv.z; se[3] += pv.w;
        }
        // butterfly over g bits (lane bits 2..5); d4 lanes keep their d-slice
#pragma unroll
        for (int off = 4; off <= 32; off <<= 1) {
#pragma unroll
            for (int m = 0; m < 4; ++m) {
                o[m][0] += __shfl_xor(o[m][0], off);
                o[m][1] += __shfl_xor(o[m][1], off);
                o[m][2] += __shfl_xor(o[m][2], off);
                o[m][3] += __shfl_xor(o[m][3], off);
                se[m]   += __shfl_xor(se[m],   off);
            }
        }
        if (g == 0) {
#pragma unroll
            for (int m = 0; m < 4; ++m) {
                float inv = 1.0f / se[m];
                float4 r; r.x = o[m][0] * inv; r.y = o[m][1] * inv;
                r.z = o[m][2] * inv; r.w = o[m][3] * inv;
                *(float4*)(O + gbase + (size_t)qn[m] * 64 + d4 * 4) = r;
            }
        }
    }
}

// ---------------------------------------------------------------------------
// Kernel 3: out_proj -> W_out -> exact GELU -> transpose to (B,N,P,C).
// 64 rows/block, same structure as kqkv.
// ---------------------------------------------------------------------------
__global__ __launch_bounds__(256) void kfinal(const float* __restrict__ Ob,
                                              const float* __restrict__ outwT,
                                              const float* __restrict__ outb,
                                              const float* __restrict__ woutT,
                                              const float* __restrict__ boutv,
                                              float* __restrict__ Yout) {
    __shared__ float xs[64 * 64];
    __shared__ float t1s[64 * 64];
    int tid = threadIdx.x;
    size_t rbase = (size_t)blockIdx.x * 64;

    const float4* xp = (const float4*)(Ob + rbase * 64);
    float4* xs4 = (float4*)xs;
#pragma unroll
    for (int i = 0; i < 4; ++i) xs4[tid + 256 * i] = xp[tid + 256 * i];
    __syncthreads();

    int j = tid & 63, r4 = tid >> 6;
    float wr[64];
#pragma unroll
    for (int cc = 0; cc < 64; ++cc) wr[cc] = outwT[cc * 64 + j];
    float bb = outb[j];
    for (int rr = r4; rr < 64; rr += 4) {
        const float* xrow = xs + rr * 64;
        float acc = bb;
#pragma unroll
        for (int cc = 0; cc < 64; ++cc) acc = fmaf(xrow[cc], wr[cc], acc);
        t1s[rr * 64 + j] = acc;
    }
    __syncthreads();

#pragma unroll
    for (int cc = 0; cc < 64; ++cc) wr[cc] = woutT[cc * 64 + j];
    float b2 = boutv[j];
    for (int rr = r4; rr < 64; rr += 4) {
        const float* trow = t1s + rr * 64;
        float acc = b2;
#pragma unroll
        for (int cc = 0; cc < 64; ++cc) acc = fmaf(trow[cc], wr[cc], acc);
        float gl = 0.5f * acc * (1.0f + erff(acc * 0.70710678118654752f));

        unsigned row = (unsigned)(rbase + rr);
        unsigned bp = row / NN, n = row - bp * NN;
        unsigned b = bp >> 6, p = bp & 63;
        size_t oidx = ((((size_t)b * NN + n) * 64 + p) * 64) + j;
        Yout[oidx] = gl;
    }
}

// ---------------------------------------------------------------------------
extern "C" void kernel_launch(void* const* d_in, const int* in_sizes, int n_in,
                              void* d_out, int out_size, void* d_ws, size_t ws_size,
                              hipStream_t stream) {
    const float* x    = (const float*)d_in[0];
    const int*   adj  = (const int*)  d_in[1];
    const float* W_in = (const float*)d_in[2];
    const float* b_in = (const float*)d_in[3];
    const float* ipw  = (const float*)d_in[4];
    const float* ipb  = (const float*)d_in[5];
    const float* outw = (const float*)d_in[6];
    const float* outb = (const float*)d_in[7];
    const float* wout = (const float*)d_in[8];
    const float* bout = (const float*)d_in[9];
    float* out = (float*)d_out;

    float* ws   = (float*)d_ws;
    float* bufQ = ws;
    float* bufK = ws + RELEM;
    float* bufV = ws + 2 * RELEM;
    float* bufO = ws + 3 * RELEM;
    float* wt   = ws + 4 * RELEM;                       // 20480 floats
    unsigned long long* MB = (unsigned long long*)(ws + 4 * RELEM + 20480);

    hipLaunchKernelGGL(kprep,  dim3(80), dim3(256), 0, stream, ipw, outw, wout, wt);
    hipLaunchKernelGGL(kmask,  dim3(8),  dim3(256), 0, stream, adj, MB);
    hipLaunchKernelGGL(kqkv,   dim3(NROWS / 64), dim3(256), 0, stream,
                       x, W_in, b_in, wt, ipb, bufQ, bufK, bufV);
    hipLaunchKernelGGL(kattn,  dim3(512 * 4), dim3(256), 0, stream,
                       bufQ, bufK, bufV, MB, bufO);
    hipLaunchKernelGGL(kfinal, dim3(NROWS / 64), dim3(256), 0, stream,
                       bufO, wt + 12288, outb, wt + 16384, bout, out);
}

// Round 4
// 360.304 us; speedup vs baseline: 7.3413x; 4.0533x over previous
//
#include <hip/hip_runtime.h>
#include <math.h>

// Problem constants
#define NN 325            // nodes (attention sequence length)
#define NI 512            // "bp" batch index of the (B*P, N, H) view
#define NROWS (8*325*64)  // 166400 flat rows of width 64
#define RELEM ((size_t)NROWS * 64)

using bf16x8 = __attribute__((ext_vector_type(8))) short;
using f32x4  = __attribute__((ext_vector_type(4))) float;

// float -> bf16 bits, round-to-nearest-even (values here are small & finite)
static __device__ inline short f2bf(float f) {
    unsigned u = __float_as_uint(f);
    unsigned r = (u + 0x7fffu + ((u >> 16) & 1u)) >> 16;
    return (short)r;
}

// ---------------------------------------------------------------------------
// Kernel 0: transpose weights so GEMM inner loops read k-major (row = k).
//  wt[0     .. 12288) : ipwT[t*4096 + k*64 + j] = in_proj_w[(t*64+j)*64+k]
//  wt[12288 .. 16384) : outwT[k*64 + j]         = out_w[j*64+k]
//  wt[16384 .. 20480) : woutT[h*64 + c]         = W_out[c*64+h]
// ---------------------------------------------------------------------------
__global__ __launch_bounds__(256) void kprep(const float* __restrict__ ipw,
                                             const float* __restrict__ outw,
                                             const float* __restrict__ wout,
                                             float* __restrict__ wt) {
    int idx = blockIdx.x * 256 + threadIdx.x;
    if (idx < 12288) {
        int t = idx >> 12, rem = idx & 4095;
        int k = rem >> 6, j = rem & 63;
        wt[idx] = ipw[(t * 64 + j) * 64 + k];
    } else if (idx < 16384) {
        int i2 = idx - 12288;
        int k = i2 >> 6, j = i2 & 63;
        wt[idx] = outw[j * 64 + k];
    } else {
        int i2 = idx - 16384;
        int h = i2 >> 6, c = i2 & 63;
        wt[idx] = wout[c * 64 + h];
    }
}

// ---------------------------------------------------------------------------
// Kernel 0b: adjacency -> per-MFMA-fragment mask bytes.
// Mb[(qt*21+kt)*64 + lane], bit r = valid(n = qt*16 + (lane>>4)*4 + r,
//                                         kn = kt*16 + (lane&15))
// valid = n<325 && kn<325 && (n==kn || adj[n][kn]). 28,224 B, L1-resident.
// ---------------------------------------------------------------------------
__global__ __launch_bounds__(256) void kmaskb(const int* __restrict__ adj,
                                              unsigned char* __restrict__ Mb) {
    int t = blockIdx.x * 256 + threadIdx.x;   // 21*21*64 = 28224
    if (t < 21 * 21 * 64) {
        int lane = t & 63, kt = (t >> 6) % 21, qt = t / (21 * 64);
        int quad = lane >> 4, l15 = lane & 15;
        int kn = kt * 16 + l15;
        unsigned char by = 0;
        if (kn < NN) {
            for (int r = 0; r < 4; ++r) {
                int n = qt * 16 + quad * 4 + r;
                if (n < NN && (n == kn || adj[n * NN + kn] != 0)) by |= (unsigned char)(1 << r);
            }
        }
        Mb[t] = by;
    }
}

// ---------------------------------------------------------------------------
// Kernel 1: fused x -> h -> Q,K,V (bf16 out, Q pre-scaled by 0.25).
// 64 rows/block. 4x4 register tiles: x from LDS-transposed b128 reads,
// W from global (L2-hot) b128 reads -> 2 mem instrs per 16 FMA.
// ---------------------------------------------------------------------------
__global__ __launch_bounds__(256) void kqkv(const float* __restrict__ X,
                                            const float* __restrict__ Win,
                                            const float* __restrict__ bin,
                                            const float* __restrict__ ipwT,
                                            const float* __restrict__ ipb,
                                            short* __restrict__ Q,
                                            short* __restrict__ K,
                                            short* __restrict__ V) {
    __shared__ __align__(16) float xsT[64 * 68];   // [k][row], stride 68
    __shared__ __align__(16) float hsT[64 * 68];
    int tid = threadIdx.x;
    size_t rbase = (size_t)blockIdx.x * 64;

    {   // stage x transposed: coalesced global read, scattered LDS write
        int r0 = tid >> 4, c = tid & 15;
#pragma unroll
        for (int i = 0; i < 4; ++i) {
            int r = r0 + i * 16;
            float4 xv = *(const float4*)(X + (rbase + r) * 64 + c * 4);
            xsT[(c * 4 + 0) * 68 + r] = xv.x;
            xsT[(c * 4 + 1) * 68 + r] = xv.y;
            xsT[(c * 4 + 2) * 68 + r] = xv.z;
            xsT[(c * 4 + 3) * 68 + r] = xv.w;
        }
    }
    __syncthreads();

    int wave = tid >> 6, lane = tid & 63;
    int rq = lane >> 4, cq = lane & 15;
    int rowb = wave * 16 + rq * 4;       // block-local row base for this thread

    // GEMM1: h = x @ Win + bin   (Win is already k-major [k][j])
    {
        float acc[4][4];
        float4 bv = *(const float4*)(bin + cq * 4);
#pragma unroll
        for (int r = 0; r < 4; ++r) {
            acc[r][0] = bv.x; acc[r][1] = bv.y; acc[r][2] = bv.z; acc[r][3] = bv.w;
        }
        for (int k = 0; k < 64; ++k) {
            float4 xv = *(const float4*)(xsT + k * 68 + rowb);
            float4 wv = *(const float4*)(Win + k * 64 + cq * 4);
            float xr[4] = {xv.x, xv.y, xv.z, xv.w};
#pragma unroll
            for (int r = 0; r < 4; ++r) {
                acc[r][0] = fmaf(xr[r], wv.x, acc[r][0]);
                acc[r][1] = fmaf(xr[r], wv.y, acc[r][1]);
                acc[r][2] = fmaf(xr[r], wv.z, acc[r][2]);
                acc[r][3] = fmaf(xr[r], wv.w, acc[r][3]);
            }
        }
#pragma unroll
        for (int r = 0; r < 4; ++r)
#pragma unroll
            for (int c = 0; c < 4; ++c)
                hsT[(cq * 4 + c) * 68 + rowb + r] = acc[r][c];
        // no barrier: this wave only reads back its own 16 rows (lgkmcnt orders)
    }

    // GEMM2..4: q,k,v = h @ ipwT_t + ipb_t  -> bf16 global
#pragma unroll
    for (int t = 0; t < 3; ++t) {
        float acc[4][4];
        float4 bv = *(const float4*)(ipb + t * 64 + cq * 4);
#pragma unroll
        for (int r = 0; r < 4; ++r) {
            acc[r][0] = bv.x; acc[r][1] = bv.y; acc[r][2] = bv.z; acc[r][3] = bv.w;
        }
        const float* W = ipwT + t * 4096;
        for (int k = 0; k < 64; ++k) {
            float4 xv = *(const float4*)(hsT + k * 68 + rowb);
            float4 wv = *(const float4*)(W + k * 64 + cq * 4);
            float xr[4] = {xv.x, xv.y, xv.z, xv.w};
#pragma unroll
            for (int r = 0; r < 4; ++r) {
                acc[r][0] = fmaf(xr[r], wv.x, acc[r][0]);
                acc[r][1] = fmaf(xr[r], wv.y, acc[r][1]);
                acc[r][2] = fmaf(xr[r], wv.z, acc[r][2]);
                acc[r][3] = fmaf(xr[r], wv.w, acc[r][3]);
            }
        }
        float sc = (t == 0) ? 0.25f : 1.0f;   // fold 1/sqrt(hd) into Q (exact in bf16)
        short* Out = (t == 0) ? Q : (t == 1) ? K : V;
#pragma unroll
        for (int r = 0; r < 4; ++r) {
            short4 s4;
            s4.x = f2bf(acc[r][0] * sc); s4.y = f2bf(acc[r][1] * sc);
            s4.z = f2bf(acc[r][2] * sc); s4.w = f2bf(acc[r][3] * sc);
            *(short4*)(Out + (rbase + rowb + r) * 64 + cq * 4) = s4;
        }
    }
}

// ---------------------------------------------------------------------------
// Kernel 2: masked MHA via MFMA. One block per (i=bp, head), 4 waves, one
// barrier. Per q-tile (16 rows): S = Q·K^T (k padded 16->32 with a zero row),
// mask+exp from Mb bytes, P->bf16 through per-wave double-buffered LDS chunk
// (C-layout -> A-layout round trip), PV MFMA accumulates 16x16 O.
// Denominator = row-sum of P, 4-step shuffle butterfly. LDS 37.9 KB -> 4/CU.
// ---------------------------------------------------------------------------
__global__ __launch_bounds__(256) void kattn(const short* __restrict__ Q,
                                             const short* __restrict__ K,
                                             const short* __restrict__ V,
                                             const unsigned char* __restrict__ Mb,
                                             float* __restrict__ O) {
    __shared__ __align__(16) short ks[337 * 24];      // [kn][k(16)+zeros], row 336 = zero row
    __shared__ __align__(16) short vsT[16 * 360];     // [d][kn], kn padded to 352 w/ zeros
    __shared__ __align__(16) short ps[4][2][16 * 40]; // per-wave dbuf P chunk [m][kn32]

    int i = blockIdx.x >> 2, head = blockIdx.x & 3;
    const short* Kb = K + (size_t)i * (NN * 64) + head * 16;
    const short* Vb = V + (size_t)i * (NN * 64) + head * 16;
    const short* Qb = Q + (size_t)i * (NN * 64) + head * 16;
    float*       Ob = O + (size_t)i * (NN * 64) + head * 16;
    int tid = threadIdx.x;

    // stage K (row-major, 16 real k + 16 zeros) and V transposed [d][kn]
    for (int kn = tid; kn < 337; kn += 256) {
        bf16x8 a = {0,0,0,0,0,0,0,0}, b = {0,0,0,0,0,0,0,0};
        bf16x8 z = {0,0,0,0,0,0,0,0};
        if (kn < NN) {
            a = *(const bf16x8*)(Kb + (size_t)kn * 64);
            b = *(const bf16x8*)(Kb + (size_t)kn * 64 + 8);
        }
        *(bf16x8*)(ks + kn * 24 + 0) = a;
        *(bf16x8*)(ks + kn * 24 + 8) = b;
        (void)z;
    }
    for (int kn = tid; kn < 352; kn += 256) {
        bf16x8 a = {0,0,0,0,0,0,0,0}, b = {0,0,0,0,0,0,0,0};
        if (kn < NN) {
            a = *(const bf16x8*)(Vb + (size_t)kn * 64);
            b = *(const bf16x8*)(Vb + (size_t)kn * 64 + 8);
        }
#pragma unroll
        for (int d = 0; d < 8; ++d) vsT[d * 360 + kn] = a[d];
#pragma unroll
        for (int d = 0; d < 8; ++d) vsT[(8 + d) * 360 + kn] = b[d];
    }
    __syncthreads();   // the only barrier

    int wave = tid >> 6, lane = tid & 63;
    int quad = lane >> 4, l15 = lane & 15;

    for (int qt = wave; qt < 21; qt += 4) {
        // A-frag: Q[m=l15][k=quad*8+j] (quads 2,3 = zero pad)
        int qrow = qt * 16 + l15; if (qrow > NN - 1) qrow = NN - 1;
        bf16x8 af = {0,0,0,0,0,0,0,0};
        if (quad < 2) af = *(const bf16x8*)(Qb + (size_t)qrow * 64 + quad * 8);

        f32x4 acc = {0.f, 0.f, 0.f, 0.f};
        float se[4] = {0.f, 0.f, 0.f, 0.f};
        short* myps = &ps[wave][0][0];

        for (int ck = 0; ck < 11; ++ck) {
            short* pchunk = myps + (ck & 1) * 640;
#pragma unroll
            for (int st = 0; st < 2; ++st) {
                int kt = ck * 2 + st;
                if (kt <= 20) {
                    // B-frag: K^T[k][kn]; quads 2,3 read the zero row
                    int koff = (quad < 2) ? (kt * 16 + l15) * 24 + quad * 8
                                          : 336 * 24 + (quad & 1) * 8;
                    bf16x8 bf = *(const bf16x8*)(ks + koff);
                    f32x4 zc = {0.f, 0.f, 0.f, 0.f};
                    f32x4 s = __builtin_amdgcn_mfma_f32_16x16x32_bf16(af, bf, zc, 0, 0, 0);
                    unsigned mb = Mb[(qt * 21 + kt) * 64 + lane];
#pragma unroll
                    for (int r = 0; r < 4; ++r) {
                        float e = __expf(s[r]);
                        float p = (mb & (1u << r)) ? e : 0.0f;
                        se[r] += p;
                        pchunk[(quad * 4 + r) * 40 + st * 16 + l15] = f2bf(p);
                    }
                    if (kt == 20) {   // zero the never-written st=1 half of chunk 10
#pragma unroll
                        for (int r = 0; r < 4; ++r)
                            pchunk[(quad * 4 + r) * 40 + 16 + l15] = 0;
                    }
                }
            }
            // PV: A = P[m=l15][k=quad*8+j], B = V[k=kn][n=d=l15]
            bf16x8 pa = *(const bf16x8*)(pchunk + l15 * 40 + quad * 8);
            bf16x8 vb = *(const bf16x8*)(vsT + l15 * 360 + ck * 32 + quad * 8);
            acc = __builtin_amdgcn_mfma_f32_16x16x32_bf16(pa, vb, acc, 0, 0, 0);
        }

        // denominator: butterfly over lane bits 0..3 (kn-lanes within quad)
#pragma unroll
        for (int off = 1; off <= 8; off <<= 1) {
#pragma unroll
            for (int r = 0; r < 4; ++r) se[r] += __shfl_xor(se[r], off);
        }
#pragma unroll
        for (int r = 0; r < 4; ++r) {
            int qn = qt * 16 + quad * 4 + r;
            if (qn < NN) {
                float inv = 1.0f / se[r];
                Ob[(size_t)qn * 64 + l15] = acc[r] * inv;
            }
        }
    }
}

// ---------------------------------------------------------------------------
// Kernel 3: out_proj -> W_out -> exact GELU -> transpose to (B,N,P,C).
// fp32 throughout (final-output precision). Same 4x4 register tiling.
// ---------------------------------------------------------------------------
__global__ __launch_bounds__(256) void kfinal(const float* __restrict__ Ob,
                                              const float* __restrict__ outwT,
                                              const float* __restrict__ outb,
                                              const float* __restrict__ woutT,
                                              const float* __restrict__ boutv,
                                              float* __restrict__ Yout) {
    __shared__ __align__(16) float xsT[64 * 68];
    __shared__ __align__(16) float tsT[64 * 68];
    int tid = threadIdx.x;
    size_t rbase = (size_t)blockIdx.x * 64;

    {
        int r0 = tid >> 4, c = tid & 15;
#pragma unroll
        for (int i = 0; i < 4; ++i) {
            int r = r0 + i * 16;
            float4 xv = *(const float4*)(Ob + (rbase + r) * 64 + c * 4);
            xsT[(c * 4 + 0) * 68 + r] = xv.x;
            xsT[(c * 4 + 1) * 68 + r] = xv.y;
            xsT[(c * 4 + 2) * 68 + r] = xv.z;
            xsT[(c * 4 + 3) * 68 + r] = xv.w;
        }
    }
    __syncthreads();

    int wave = tid >> 6, lane = tid & 63;
    int rq = lane >> 4, cq = lane & 15;
    int rowb = wave * 16 + rq * 4;

    // GEMM1: t1 = o @ out_w^T + out_b
    {
        float acc[4][4];
        float4 bv = *(const float4*)(outb + cq * 4);
#pragma unroll
        for (int r = 0; r < 4; ++r) {
            acc[r][0] = bv.x; acc[r][1] = bv.y; acc[r][2] = bv.z; acc[r][3] = bv.w;
        }
        for (int k = 0; k < 64; ++k) {
            float4 xv = *(const float4*)(xsT + k * 68 + rowb);
            float4 wv = *(const float4*)(outwT + k * 64 + cq * 4);
            float xr[4] = {xv.x, xv.y, xv.z, xv.w};
#pragma unroll
            for (int r = 0; r < 4; ++r) {
                acc[r][0] = fmaf(xr[r], wv.x, acc[r][0]);
                acc[r][1] = fmaf(xr[r], wv.y, acc[r][1]);
                acc[r][2] = fmaf(xr[r], wv.z, acc[r][2]);
                acc[r][3] = fmaf(xr[r], wv.w, acc[r][3]);
            }
        }
#pragma unroll
        for (int r = 0; r < 4; ++r)
#pragma unroll
            for (int c = 0; c < 4; ++c)
                tsT[(cq * 4 + c) * 68 + rowb + r] = acc[r][c];
    }
    // wave-local read-back: no barrier needed

    // GEMM2 + GELU + transposed store
    {
        float acc[4][4];
        float4 bv = *(const float4*)(boutv + cq * 4);
#pragma unroll
        for (int r = 0; r < 4; ++r) {
            acc[r][0] = bv.x; acc[r][1] = bv.y; acc[r][2] = bv.z; acc[r][3] = bv.w;
        }
        for (int k = 0; k < 64; ++k) {
            float4 xv = *(const float4*)(tsT + k * 68 + rowb);
            float4 wv = *(const float4*)(woutT + k * 64 + cq * 4);
            float xr[4] = {xv.x, xv.y, xv.z, xv.w};
#pragma unroll
            for (int r = 0; r < 4; ++r) {
                acc[r][0] = fmaf(xr[r], wv.x, acc[r][0]);
                acc[r][1] = fmaf(xr[r], wv.y, acc[r][1]);
                acc[r][2] = fmaf(xr[r], wv.z, acc[r][2]);
                acc[r][3] = fmaf(xr[r], wv.w, acc[r][3]);
            }
        }
#pragma unroll
        for (int r = 0; r < 4; ++r) {
            unsigned row = (unsigned)(rbase + rowb + r);   // flat (i, n): i=row/325
            unsigned ii = row / NN, n = row - ii * NN;
            unsigned b = ii >> 6, p = ii & 63;
            size_t oidx = ((((size_t)b * NN + n) * 64 + p) * 64) + cq * 4;
            float4 yv;
            float a0 = acc[r][0], a1 = acc[r][1], a2 = acc[r][2], a3 = acc[r][3];
            yv.x = 0.5f * a0 * (1.0f + erff(a0 * 0.70710678118654752f));
            yv.y = 0.5f * a1 * (1.0f + erff(a1 * 0.70710678118654752f));
            yv.z = 0.5f * a2 * (1.0f + erff(a2 * 0.70710678118654752f));
            yv.w = 0.5f * a3 * (1.0f + erff(a3 * 0.70710678118654752f));
            *(float4*)(Yout + oidx) = yv;
        }
    }
}

// ---------------------------------------------------------------------------
extern "C" void kernel_launch(void* const* d_in, const int* in_sizes, int n_in,
                              void* d_out, int out_size, void* d_ws, size_t ws_size,
                              hipStream_t stream) {
    const float* x    = (const float*)d_in[0];
    const int*   adj  = (const int*)  d_in[1];
    const float* W_in = (const float*)d_in[2];
    const float* b_in = (const float*)d_in[3];
    const float* ipw  = (const float*)d_in[4];
    const float* ipb  = (const float*)d_in[5];
    const float* outw = (const float*)d_in[6];
    const float* outb = (const float*)d_in[7];
    const float* wout = (const float*)d_in[8];
    const float* bout = (const float*)d_in[9];
    float* out = (float*)d_out;

    char* wsb = (char*)d_ws;
    short* bufQ = (short*)(wsb);                        // 2*RELEM bytes
    short* bufK = (short*)(wsb + 2 * RELEM);
    short* bufV = (short*)(wsb + 4 * RELEM);
    float* bufO = (float*)(wsb + 6 * RELEM);            // 4*RELEM bytes
    float* wt   = (float*)(wsb + 10 * RELEM);           // 20480 floats
    unsigned char* Mb = (unsigned char*)(wsb + 10 * RELEM + 20480 * 4);  // 28224 B

    hipLaunchKernelGGL(kprep,  dim3(80),  dim3(256), 0, stream, ipw, outw, wout, wt);
    hipLaunchKernelGGL(kmaskb, dim3(111), dim3(256), 0, stream, adj, Mb);
    hipLaunchKernelGGL(kqkv,   dim3(NROWS / 64), dim3(256), 0, stream,
                       x, W_in, b_in, wt, ipb, bufQ, bufK, bufV);
    hipLaunchKernelGGL(kattn,  dim3(NI * 4), dim3(256), 0, stream,
                       bufQ, bufK, bufV, Mb, bufO);
    hipLaunchKernelGGL(kfinal, dim3(NROWS / 64), dim3(256), 0, stream,
                       bufO, wt + 12288, outb, wt + 16384, bout, out);
}

// Round 5
// 318.530 us; speedup vs baseline: 8.3040x; 1.1311x over previous
//
#include <hip/hip_runtime.h>
#include <hip/hip_bf16.h>
#include <math.h>

// Problem constants
#define NN 325            // nodes (attention sequence length)
#define NROWS (8*325*64)  // 166400 flat rows of width 64
#define RELEM ((size_t)NROWS * 64)
#define NTILES (NROWS/16) // 10400 16-row tiles
#define QSC 0.36067376022224085f   // 0.25 * log2(e): exp2-domain softmax

using bf16x8 = __attribute__((ext_vector_type(8))) short;
using f32x4  = __attribute__((ext_vector_type(4))) float;

union BF8 { bf16x8 v; unsigned u[4]; };

// float -> bf16 bits, RNE (scalar; used in prep only)
static __device__ inline short f2bf(float f) {
    unsigned u = __float_as_uint(f);
    unsigned r = (u + 0x7fffu + ((u >> 16) & 1u)) >> 16;
    return (short)r;
}
// packed pair: low 16 = bf16(a), high 16 = bf16(b)
static __device__ inline unsigned pk2(float a, float b) {
    __hip_bfloat162 h = __float22bfloat162_rn(make_float2(a, b));
    union { __hip_bfloat162 h; unsigned u; } c; c.h = h; return c.u;
}

// ---------------------------------------------------------------------------
// Kernel 0: pack 6 weight matrices into MFMA-A-frag-linear hi/lo bf16 planes.
// Matrices (all A[m][k], 64x64): 0: W_in^T  1..3: in_proj rows q,k,v
//                                4: out_w   5: W_out
// Layout: Wp[mat*8192 + (mt*2+kc)*1024 + plane*512 + lane*8 + j]
//   element A[m = mt*16 + (lane&15)][k = kc*32 + (lane>>4)*8 + j]
// ---------------------------------------------------------------------------
__global__ __launch_bounds__(256) void kprep(const float* __restrict__ Win,
                                             const float* __restrict__ ipw,
                                             const float* __restrict__ outw,
                                             const float* __restrict__ wout,
                                             short* __restrict__ Wp) {
    int idx = blockIdx.x * 256 + threadIdx.x;   // 6*4096 = 24576
    if (idx >= 24576) return;
    int mat = idx >> 12, ft = (idx >> 9) & 7, lane = (idx >> 3) & 63, j = idx & 7;
    int m = (ft >> 1) * 16 + (lane & 15);
    int k = (ft & 1) * 32 + (lane >> 4) * 8 + j;
    float w;
    if (mat == 0)      w = Win[k * 64 + m];               // W_in^T
    else if (mat <= 3) w = ipw[((mat - 1) * 64 + m) * 64 + k];
    else if (mat == 4) w = outw[m * 64 + k];
    else               w = wout[m * 64 + k];
    short hi = f2bf(w);
    float hif = __uint_as_float(((unsigned)(unsigned short)hi) << 16);
    short lo = f2bf(w - hif);
    int base = mat * 8192 + ft * 1024 + lane * 8 + j;
    Wp[base] = hi;
    Wp[base + 512] = lo;
}

// ---------------------------------------------------------------------------
// Kernel 0b: adjacency -> additive score bias in S-fragment layout.
// Sb[((qt*21+kt)*64 + lane)*4 + r] = valid ? 0 : -inf
//   n = qt*16 + (lane>>4)*4 + r, kn = kt*16 + (lane&15)
// 451.6 KB fp32, L2-resident; loaded as MFMA C-init (no mask VALU at all).
// ---------------------------------------------------------------------------
__global__ __launch_bounds__(256) void kbias(const int* __restrict__ adj,
                                             float* __restrict__ Sb) {
    int idx = blockIdx.x * 256 + threadIdx.x;   // 21*21*64 = 28224
    if (idx < 21 * 21 * 64) {
        int lane = idx & 63, kt = (idx >> 6) % 21, qt = idx / (21 * 64);
        int quad = lane >> 4, l15 = lane & 15;
        int kn = kt * 16 + l15;
        float bb[4];
#pragma unroll
        for (int r = 0; r < 4; ++r) {
            int n = qt * 16 + quad * 4 + r;
            bool valid = (n < NN) && (kn < NN) &&
                         (n == kn || adj[n * NN + kn] != 0);
            bb[r] = valid ? 0.0f : -INFINITY;
        }
        float4 v; v.x = bb[0]; v.y = bb[1]; v.z = bb[2]; v.w = bb[3];
        *(float4*)(Sb + (size_t)idx * 4) = v;
    }
}

// ---------------------------------------------------------------------------
// Kernel 1: fused x -> h -> Q,K,V via bf16x3 MFMA (hi/lo split, 3 MFMA per
// product: ~2e-5 rel err). Transposed formulation: C = (out)^T so A-operands
// are the packed weights and stores are coalesced b64. h chained through a
// per-wave LDS frag buffer (no barriers in the loop). Q pre-scaled for
// exp2-domain softmax. LDS = 64K weights + 16K h = exactly 80 KB -> 2/CU.
// ---------------------------------------------------------------------------
__global__ __launch_bounds__(256, 2) void kqkv(const float* __restrict__ X,
                                               const float* __restrict__ bin,
                                               const float* __restrict__ ipb,
                                               const short* __restrict__ Wp,
                                               short* __restrict__ Q,
                                               short* __restrict__ Kb,
                                               short* __restrict__ Vb) {
    __shared__ short wl[32768];     // mats 0..3 frag-linear (65,536 B)
    __shared__ short hf[4][2048];   // per-wave h frags hi/lo (16,384 B)
    int tid = threadIdx.x;
    {   // stage weights (one-time)
        const uint4* src = (const uint4*)Wp;
        uint4* dst = (uint4*)wl;
#pragma unroll
        for (int i = 0; i < 16; ++i) dst[tid + i * 256] = src[tid + i * 256];
    }
    __syncthreads();

    int wave = tid >> 6, lane = tid & 63, quad = lane >> 4, l15 = lane & 15;
    short* hfw = hf[wave];

    for (int tile = blockIdx.x * 4 + wave; tile < NTILES; tile += gridDim.x * 4) {
        size_t row = (size_t)tile * 16 + l15;

        // ---- x B-frags (fp32 -> hi/lo bf16) ----
        BF8 xbh[2], xbl[2];
#pragma unroll
        for (int kc = 0; kc < 2; ++kc) {
            const float* xp = X + row * 64 + kc * 32 + quad * 8;
            float4 v0 = *(const float4*)xp;
            float4 v1 = *(const float4*)(xp + 4);
            float e[8] = {v0.x, v0.y, v0.z, v0.w, v1.x, v1.y, v1.z, v1.w};
            unsigned hh[4], ll[4];
#pragma unroll
            for (int p = 0; p < 4; ++p) {
                hh[p] = pk2(e[2 * p], e[2 * p + 1]);
                float f0 = __uint_as_float(hh[p] << 16);
                float f1 = __uint_as_float(hh[p] & 0xFFFF0000u);
                ll[p] = pk2(e[2 * p] - f0, e[2 * p + 1] - f1);
            }
#pragma unroll
            for (int p = 0; p < 4; ++p) { xbh[kc].u[p] = hh[p]; xbl[kc].u[p] = ll[p]; }
        }

        // ---- GEMM1: h^T = W_in^T x^T + b_in ----
#pragma unroll
        for (int mt = 0; mt < 4; ++mt) {
            float4 bv = *(const float4*)(bin + mt * 16 + quad * 4);
            f32x4 acc = {bv.x, bv.y, bv.z, bv.w};
#pragma unroll
            for (int kc = 0; kc < 2; ++kc) {
                const short* ap = wl + (mt * 2 + kc) * 1024 + lane * 8;
                bf16x8 ah = *(const bf16x8*)ap;
                bf16x8 al = *(const bf16x8*)(ap + 512);
                acc = __builtin_amdgcn_mfma_f32_16x16x32_bf16(ah, xbh[kc].v, acc, 0, 0, 0);
                acc = __builtin_amdgcn_mfma_f32_16x16x32_bf16(ah, xbl[kc].v, acc, 0, 0, 0);
                acc = __builtin_amdgcn_mfma_f32_16x16x32_bf16(al, xbh[kc].v, acc, 0, 0, 0);
            }
            // write h hi/lo frags: F = mt*16+quad*4+r, R = l15
            int kc2 = mt >> 1;
            int lane2 = ((mt & 1) * 2 + (quad >> 1)) * 16 + l15;
            int jb = (quad & 1) * 4;
            unsigned u01 = pk2(acc[0], acc[1]), u23 = pk2(acc[2], acc[3]);
            uint2 wh; wh.x = u01; wh.y = u23;
            *(uint2*)(hfw + kc2 * 1024 + lane2 * 8 + jb) = wh;
            float f0 = __uint_as_float(u01 << 16), f1 = __uint_as_float(u01 & 0xFFFF0000u);
            float f2 = __uint_as_float(u23 << 16), f3 = __uint_as_float(u23 & 0xFFFF0000u);
            uint2 wlo; wlo.x = pk2(acc[0] - f0, acc[1] - f1);
            wlo.y = pk2(acc[2] - f2, acc[3] - f3);
            *(uint2*)(hfw + kc2 * 1024 + 512 + lane2 * 8 + jb) = wlo;
        }

        // ---- h B-frags (wave-private readback; lgkmcnt orders) ----
        BF8 hbh[2], hbl[2];
#pragma unroll
        for (int kc = 0; kc < 2; ++kc) {
            hbh[kc].v = *(const bf16x8*)(hfw + kc * 1024 + lane * 8);
            hbl[kc].v = *(const bf16x8*)(hfw + kc * 1024 + 512 + lane * 8);
        }

        // ---- GEMM2-4: q^T,k^T,v^T = W_t h^T + b_t ----
#pragma unroll
        for (int t = 0; t < 3; ++t) {
            short* Out = (t == 0) ? Q : (t == 1) ? Kb : Vb;
            float sc = (t == 0) ? QSC : 1.0f;
#pragma unroll
            for (int mt = 0; mt < 4; ++mt) {
                float4 bv = *(const float4*)(ipb + t * 64 + mt * 16 + quad * 4);
                f32x4 acc = {bv.x, bv.y, bv.z, bv.w};
#pragma unroll
                for (int kc = 0; kc < 2; ++kc) {
                    const short* ap = wl + (1 + t) * 8192 + (mt * 2 + kc) * 1024 + lane * 8;
                    bf16x8 ah = *(const bf16x8*)ap;
                    bf16x8 al = *(const bf16x8*)(ap + 512);
                    acc = __builtin_amdgcn_mfma_f32_16x16x32_bf16(ah, hbh[kc].v, acc, 0, 0, 0);
                    acc = __builtin_amdgcn_mfma_f32_16x16x32_bf16(ah, hbl[kc].v, acc, 0, 0, 0);
                    acc = __builtin_amdgcn_mfma_f32_16x16x32_bf16(al, hbh[kc].v, acc, 0, 0, 0);
                }
                uint2 st; st.x = pk2(acc[0] * sc, acc[1] * sc);
                st.y = pk2(acc[2] * sc, acc[3] * sc);
                *(uint2*)(Out + row * 64 + mt * 16 + quad * 4) = st;
            }
        }
    }
}

// ---------------------------------------------------------------------------
// Kernel 2: masked MHA via MFMA. Bias-in-C masking (0/-inf from Sb), exp2
// softmax (Q pre-scaled), denominator via ones-vector MFMA. One barrier.
// LDS 37.9 KB -> 4 blocks/CU.
// ---------------------------------------------------------------------------
__global__ __launch_bounds__(256) void kattn(const short* __restrict__ Q,
                                             const short* __restrict__ K,
                                             const short* __restrict__ V,
                                             const float* __restrict__ Sb,
                                             float* __restrict__ O) {
    __shared__ __align__(16) short ks[337 * 24];      // row 336 = zero row
    __shared__ __align__(16) short vsT[16 * 360];     // [d][kn], zero-padded
    __shared__ __align__(16) short ps[4][2][640];     // per-wave dbuf P chunk

    int i = blockIdx.x >> 2, head = blockIdx.x & 3;
    const short* Kb = K + (size_t)i * (NN * 64) + head * 16;
    const short* Vbp = V + (size_t)i * (NN * 64) + head * 16;
    const short* Qb = Q + (size_t)i * (NN * 64) + head * 16;
    float*       Ob = O + (size_t)i * (NN * 64) + head * 16;
    int tid = threadIdx.x;

    for (int kn = tid; kn < 337; kn += 256) {
        bf16x8 a = {0,0,0,0,0,0,0,0}, b = {0,0,0,0,0,0,0,0};
        if (kn < NN) {
            a = *(const bf16x8*)(Kb + (size_t)kn * 64);
            b = *(const bf16x8*)(Kb + (size_t)kn * 64 + 8);
        }
        *(bf16x8*)(ks + kn * 24 + 0) = a;
        *(bf16x8*)(ks + kn * 24 + 8) = b;
    }
    for (int kn = tid; kn < 352; kn += 256) {
        bf16x8 a = {0,0,0,0,0,0,0,0}, b = {0,0,0,0,0,0,0,0};
        if (kn < NN) {
            a = *(const bf16x8*)(Vbp + (size_t)kn * 64);
            b = *(const bf16x8*)(Vbp + (size_t)kn * 64 + 8);
        }
#pragma unroll
        for (int d = 0; d < 8; ++d) vsT[d * 360 + kn] = a[d];
#pragma unroll
        for (int d = 0; d < 8; ++d) vsT[(8 + d) * 360 + kn] = b[d];
    }
    __syncthreads();   // the only barrier

    int wave = tid >> 6, lane = tid & 63;
    int quad = lane >> 4, l15 = lane & 15;
    bf16x8 ones;
#pragma unroll
    for (int z = 0; z < 8; ++z) ones[z] = (short)0x3F80;   // bf16 1.0

    for (int qt = wave; qt < 21; qt += 4) {
        int qrow = qt * 16 + l15; if (qrow > NN - 1) qrow = NN - 1;
        bf16x8 af = {0,0,0,0,0,0,0,0};
        if (quad < 2) af = *(const bf16x8*)(Qb + (size_t)qrow * 64 + quad * 8);

        f32x4 acc = {0.f, 0.f, 0.f, 0.f};
        f32x4 dacc = {0.f, 0.f, 0.f, 0.f};
        short* myps = &ps[wave][0][0];

        for (int ck = 0; ck < 11; ++ck) {
            short* pchunk = myps + (ck & 1) * 640;
#pragma unroll
            for (int st = 0; st < 2; ++st) {
                int kt = ck * 2 + st;
                if (kt <= 20) {
                    int koff = (quad < 2) ? (kt * 16 + l15) * 24 + quad * 8
                                          : 336 * 24 + (quad & 1) * 8;
                    bf16x8 bf = *(const bf16x8*)(ks + koff);
                    float4 bb = *(const float4*)(Sb + ((size_t)(qt * 21 + kt) * 64 + lane) * 4);
                    f32x4 cb = {bb.x, bb.y, bb.z, bb.w};
                    f32x4 s = __builtin_amdgcn_mfma_f32_16x16x32_bf16(af, bf, cb, 0, 0, 0);
                    float p0 = exp2f(s[0]), p1 = exp2f(s[1]);
                    float p2 = exp2f(s[2]), p3 = exp2f(s[3]);
                    unsigned u01 = pk2(p0, p1), u23 = pk2(p2, p3);
                    int base = (quad * 4) * 40 + st * 16 + l15;
                    pchunk[base]       = (short)u01;
                    pchunk[base + 40]  = (short)(u01 >> 16);
                    pchunk[base + 80]  = (short)u23;
                    pchunk[base + 120] = (short)(u23 >> 16);
                    if (kt == 20) {   // zero the never-written st=1 half
#pragma unroll
                        for (int r = 0; r < 4; ++r)
                            pchunk[(quad * 4 + r) * 40 + 16 + l15] = 0;
                    }
                }
            }
            bf16x8 pa = *(const bf16x8*)(pchunk + l15 * 40 + quad * 8);
            bf16x8 vb = *(const bf16x8*)(vsT + l15 * 360 + ck * 32 + quad * 8);
            acc  = __builtin_amdgcn_mfma_f32_16x16x32_bf16(pa, vb,   acc,  0, 0, 0);
            dacc = __builtin_amdgcn_mfma_f32_16x16x32_bf16(pa, ones, dacc, 0, 0, 0);
        }

#pragma unroll
        for (int r = 0; r < 4; ++r) {
            int qn = qt * 16 + quad * 4 + r;
            if (qn < NN) Ob[(size_t)qn * 64 + l15] = acc[r] / dacc[r];
        }
    }
}

// ---------------------------------------------------------------------------
// Kernel 3: o -> out_proj -> W_out -> exact GELU -> transposed store, same
// bf16x3 MFMA structure. LDS 48 KB -> 3 blocks/CU.
// ---------------------------------------------------------------------------
__global__ __launch_bounds__(256, 2) void kfinal(const float* __restrict__ Ob,
                                                 const float* __restrict__ outb,
                                                 const float* __restrict__ boutv,
                                                 const short* __restrict__ Wp,
                                                 float* __restrict__ Yout) {
    __shared__ short wl[16384];     // mats 4,5 (32,768 B)
    __shared__ short hf[4][2048];   // per-wave t1 frags
    int tid = threadIdx.x;
    {
        const uint4* src = (const uint4*)Wp;
        uint4* dst = (uint4*)wl;
#pragma unroll
        for (int i = 0; i < 8; ++i) dst[tid + i * 256] = src[4096 + tid + i * 256];
    }
    __syncthreads();

    int wave = tid >> 6, lane = tid & 63, quad = lane >> 4, l15 = lane & 15;
    short* hfw = hf[wave];

    for (int tile = blockIdx.x * 4 + wave; tile < NTILES; tile += gridDim.x * 4) {
        size_t row = (size_t)tile * 16 + l15;

        BF8 obh[2], obl[2];
#pragma unroll
        for (int kc = 0; kc < 2; ++kc) {
            const float* xp = Ob + row * 64 + kc * 32 + quad * 8;
            float4 v0 = *(const float4*)xp;
            float4 v1 = *(const float4*)(xp + 4);
            float e[8] = {v0.x, v0.y, v0.z, v0.w, v1.x, v1.y, v1.z, v1.w};
            unsigned hh[4], ll[4];
#pragma unroll
            for (int p = 0; p < 4; ++p) {
                hh[p] = pk2(e[2 * p], e[2 * p + 1]);
                float f0 = __uint_as_float(hh[p] << 16);
                float f1 = __uint_as_float(hh[p] & 0xFFFF0000u);
                ll[p] = pk2(e[2 * p] - f0, e[2 * p + 1] - f1);
            }
#pragma unroll
            for (int p = 0; p < 4; ++p) { obh[kc].u[p] = hh[p]; obl[kc].u[p] = ll[p]; }
        }

        // GEMM5: t1^T = out_w o^T + out_b
#pragma unroll
        for (int mt = 0; mt < 4; ++mt) {
            float4 bv = *(const float4*)(outb + mt * 16 + quad * 4);
            f32x4 acc = {bv.x, bv.y, bv.z, bv.w};
#pragma unroll
            for (int kc = 0; kc < 2; ++kc) {
                const short* ap = wl + (mt * 2 + kc) * 1024 + lane * 8;
                bf16x8 ah = *(const bf16x8*)ap;
                bf16x8 al = *(const bf16x8*)(ap + 512);
                acc = __builtin_amdgcn_mfma_f32_16x16x32_bf16(ah, obh[kc].v, acc, 0, 0, 0);
                acc = __builtin_amdgcn_mfma_f32_16x16x32_bf16(ah, obl[kc].v, acc, 0, 0, 0);
                acc = __builtin_amdgcn_mfma_f32_16x16x32_bf16(al, obh[kc].v, acc, 0, 0, 0);
            }
            int kc2 = mt >> 1;
            int lane2 = ((mt & 1) * 2 + (quad >> 1)) * 16 + l15;
            int jb = (quad & 1) * 4;
            unsigned u01 = pk2(acc[0], acc[1]), u23 = pk2(acc[2], acc[3]);
            uint2 wh; wh.x = u01; wh.y = u23;
            *(uint2*)(hfw + kc2 * 1024 + lane2 * 8 + jb) = wh;
            float f0 = __uint_as_float(u01 << 16), f1 = __uint_as_float(u01 & 0xFFFF0000u);
            float f2 = __uint_as_float(u23 << 16), f3 = __uint_as_float(u23 & 0xFFFF0000u);
            uint2 wlo; wlo.x = pk2(acc[0] - f0, acc[1] - f1);
            wlo.y = pk2(acc[2] - f2, acc[3] - f3);
            *(uint2*)(hfw + kc2 * 1024 + 512 + lane2 * 8 + jb) = wlo;
        }

        BF8 tbh[2], tbl[2];
#pragma unroll
        for (int kc = 0; kc < 2; ++kc) {
            tbh[kc].v = *(const bf16x8*)(hfw + kc * 1024 + lane * 8);
            tbl[kc].v = *(const bf16x8*)(hfw + kc * 1024 + 512 + lane * 8);
        }

        // GEMM6: y^T = W_out t1^T + b_out; GELU; scatter store
        unsigned rw = (unsigned)row;
        unsigned ii = rw / NN, n = rw - ii * NN;
        unsigned b = ii >> 6, p = ii & 63;
        size_t obase = (((size_t)b * NN + n) * 64 + p) * 64;
#pragma unroll
        for (int mt = 0; mt < 4; ++mt) {
            float4 bv = *(const float4*)(boutv + mt * 16 + quad * 4);
            f32x4 acc = {bv.x, bv.y, bv.z, bv.w};
#pragma unroll
            for (int kc = 0; kc < 2; ++kc) {
                const short* ap = wl + 8192 + (mt * 2 + kc) * 1024 + lane * 8;
                bf16x8 ah = *(const bf16x8*)ap;
                bf16x8 al = *(const bf16x8*)(ap + 512);
                acc = __builtin_amdgcn_mfma_f32_16x16x32_bf16(ah, tbh[kc].v, acc, 0, 0, 0);
                acc = __builtin_amdgcn_mfma_f32_16x16x32_bf16(ah, tbl[kc].v, acc, 0, 0, 0);
                acc = __builtin_amdgcn_mfma_f32_16x16x32_bf16(al, tbh[kc].v, acc, 0, 0, 0);
            }
            float4 yv;
            yv.x = 0.5f * acc[0] * (1.0f + erff(acc[0] * 0.70710678118654752f));
            yv.y = 0.5f * acc[1] * (1.0f + erff(acc[1] * 0.70710678118654752f));
            yv.z = 0.5f * acc[2] * (1.0f + erff(acc[2] * 0.70710678118654752f));
            yv.w = 0.5f * acc[3] * (1.0f + erff(acc[3] * 0.70710678118654752f));
            *(float4*)(Yout + obase + mt * 16 + quad * 4) = yv;
        }
    }
}

// ---------------------------------------------------------------------------
extern "C" void kernel_launch(void* const* d_in, const int* in_sizes, int n_in,
                              void* d_out, int out_size, void* d_ws, size_t ws_size,
                              hipStream_t stream) {
    const float* x    = (const float*)d_in[0];
    const int*   adj  = (const int*)  d_in[1];
    const float* W_in = (const float*)d_in[2];
    const float* b_in = (const float*)d_in[3];
    const float* ipw  = (const float*)d_in[4];
    const float* ipb  = (const float*)d_in[5];
    const float* outw = (const float*)d_in[6];
    const float* outb = (const float*)d_in[7];
    const float* wout = (const float*)d_in[8];
    const float* bout = (const float*)d_in[9];
    float* out = (float*)d_out;

    char* wsb = (char*)d_ws;
    short* bufQ = (short*)(wsb);                        // 2*RELEM B
    short* bufK = (short*)(wsb + 2 * RELEM);
    short* bufV = (short*)(wsb + 4 * RELEM);
    float* bufO = (float*)(wsb + 6 * RELEM);            // 4*RELEM B
    short* Wp   = (short*)(wsb + 10 * RELEM);           // 98,304 B
    float* Sb   = (float*)(wsb + 10 * RELEM + 98304);   // 451,584 B

    hipLaunchKernelGGL(kprep,  dim3(96),  dim3(256), 0, stream, W_in, ipw, outw, wout, Wp);
    hipLaunchKernelGGL(kbias,  dim3(111), dim3(256), 0, stream, adj, Sb);
    hipLaunchKernelGGL(kqkv,   dim3(512), dim3(256), 0, stream,
                       x, b_in, ipb, Wp, bufQ, bufK, bufV);
    hipLaunchKernelGGL(kattn,  dim3(512 * 4), dim3(256), 0, stream,
                       bufQ, bufK, bufV, Sb, bufO);
    hipLaunchKernelGGL(kfinal, dim3(768), dim3(256), 0, stream,
                       bufO, outb, bout, Wp, out);
}